// Round 1
// baseline (2558.268 us; speedup 1.0000x reference)
//
#include <hip/hip_runtime.h>
#include <math.h>

// SegmentalLM forward, fp32 reference-faithful implementation.
// V=4000 E=H=256 M=128 B=32 L=4, S=126, SB=4032, NROW=5*4032=20160.

#define LOGNEG -1000000.0f
#define GF_BIAS 1
#define GF_TANH 2
#define GF_DECSTEP 4
#define GF_ACC 8

__device__ __forceinline__ float sigmf_(float x){ return 1.0f/(1.0f+expf(-x)); }

// ---------------- embed + is_single ----------------
// grid 4096 blocks (ri = m*32+b), 256 threads (h)
__global__ __launch_bounds__(256) void k_embed(
    const int* __restrict__ x, const float* __restrict__ emb,
    float* __restrict__ emb_in, float* __restrict__ is_s)
{
    int ri = blockIdx.x;
    int m = ri >> 5, b = ri & 31;
    int tok = x[b*128 + m];
    int h = threadIdx.x;
    emb_in[(size_t)ri*256 + h] = emb[(size_t)tok*256 + h];
    if (h == 0) is_s[ri] = (tok <= 2) ? LOGNEG : 0.0f;
}

// ---------------- transpose enc_Whh + bias sums ----------------
// grid 1024 (j), 256 threads (k)
__global__ __launch_bounds__(256) void k_prep(
    const float* __restrict__ Whh, float* __restrict__ WhhT,
    const float* __restrict__ ebih, const float* __restrict__ ebhh, float* __restrict__ bias_e,
    const float* __restrict__ dbih, const float* __restrict__ dbhh, float* __restrict__ bias_d)
{
    int j = blockIdx.x;
    int k = threadIdx.x;
    WhhT[k*1024 + j] = Whh[j*256 + k];
    if (k == 0){ bias_e[j] = ebih[j]+ebhh[j]; bias_d[j] = dbih[j]+dbhh[j]; }
}

// ---------------- generic tiled GEMM: C = A(M,K) @ W(N,K)^T (+bias)(+acc)(+decstep base)(tanh) ----------------
// 64x64 tile, BK=16, 256 threads, 4x4 micro. All dims multiples of 64 / K=256.
__global__ __launch_bounds__(256) void k_gemm(
    const float* __restrict__ A, const float* __restrict__ W,
    const float* __restrict__ bias, float* __restrict__ C,
    int K, int N, int flags,
    const float* __restrict__ XgI, const float* __restrict__ bsum, int jstep)
{
    __shared__ float As[16][68];
    __shared__ float Bs[16][68];
    int tid = threadIdx.x;
    int tx = tid & 15, ty = tid >> 4;
    int rowBlk = blockIdx.y * 64, colBlk = blockIdx.x * 64;
    int lr = tid >> 2;
    int lk = (tid & 3) * 4;
    const float* Aload = A + (size_t)(rowBlk + lr)*K + lk;
    const float* Wload = W + (size_t)(colBlk + lr)*K + lk;
    float acc[4][4] = {};
    for (int kt = 0; kt < K; kt += 16){
        float4 av = *(const float4*)(Aload + kt);
        float4 wv = *(const float4*)(Wload + kt);
        As[lk+0][lr] = av.x; As[lk+1][lr] = av.y; As[lk+2][lr] = av.z; As[lk+3][lr] = av.w;
        Bs[lk+0][lr] = wv.x; Bs[lk+1][lr] = wv.y; Bs[lk+2][lr] = wv.z; Bs[lk+3][lr] = wv.w;
        __syncthreads();
        #pragma unroll
        for (int k = 0; k < 16; k++){
            float4 a4 = *(const float4*)&As[k][ty*4];
            float4 b4 = *(const float4*)&Bs[k][tx*4];
            acc[0][0] += a4.x*b4.x; acc[0][1] += a4.x*b4.y; acc[0][2] += a4.x*b4.z; acc[0][3] += a4.x*b4.w;
            acc[1][0] += a4.y*b4.x; acc[1][1] += a4.y*b4.y; acc[1][2] += a4.y*b4.z; acc[1][3] += a4.y*b4.w;
            acc[2][0] += a4.z*b4.x; acc[2][1] += a4.z*b4.y; acc[2][2] += a4.z*b4.z; acc[2][3] += a4.z*b4.w;
            acc[3][0] += a4.w*b4.x; acc[3][1] += a4.w*b4.y; acc[3][2] += a4.w*b4.z; acc[3][3] += a4.w*b4.w;
        }
        __syncthreads();
    }
    #pragma unroll
    for (int i = 0; i < 4; i++){
        int r = rowBlk + ty*4 + i;
        #pragma unroll
        for (int j = 0; j < 4; j++){
            int c = colBlk + tx*4 + j;
            float v = acc[i][j];
            if (flags & GF_ACC)  v += C[(size_t)r*N + c];
            if (flags & GF_BIAS) v += bias[c];
            if (flags & GF_DECSTEP){
                int s = r >> 5, b = r & 31;
                int m = s + jstep;
                v += (m < 128) ? XgI[((size_t)(m*32+b))*1024 + c] : bsum[c];
            }
            if (flags & GF_TANH) v = tanhf(v);
            C[(size_t)r*N + c] = v;
        }
    }
}

// ---------------- encoder LSTM recurrence: 32 blocks (batch row), 1024 threads ----------------
// Batch rows are independent -> no grid sync. Xg holds input-side gates (+biases).
__global__ __launch_bounds__(1024) void k_enc_rnn(
    const float* __restrict__ Xg, const float* __restrict__ WhhT,
    const float* __restrict__ h0, const float* __restrict__ c0,
    float* __restrict__ enc_out)
{
    int b = blockIdx.x, tid = threadIdx.x;
    __shared__ float h_s[256];
    __shared__ float g_s[1024];
    float c = 0.0f;
    if (tid < 256){ h_s[tid] = h0[tid]; c = c0[tid]; }
    __syncthreads();
    const float* wp = WhhT + tid;
    for (int t = 0; t < 128; t++){
        float g = Xg[((size_t)(t*32+b))*1024 + tid];
        #pragma unroll 8
        for (int k = 0; k < 256; k++) g += h_s[k] * wp[k*1024];
        g_s[tid] = g;
        __syncthreads();
        if (tid < 256){
            float gi = g_s[tid], gf = g_s[256+tid], gg = g_s[512+tid], go = g_s[768+tid];
            c = sigmf_(gf)*c + sigmf_(gi)*tanhf(gg);
            float hn = sigmf_(go)*tanhf(c);
            h_s[tid] = hn;
            enc_out[((size_t)(t*32+b))*256 + tid] = 0.5f*hn;
        }
        __syncthreads();
    }
}

// ---------------- decoder LSTM pointwise update ----------------
__global__ __launch_bounds__(256) void k_pointwise(
    const float* __restrict__ gbuf, float* __restrict__ h, float* __restrict__ c,
    float* __restrict__ dec_out_j)
{
    int sb = blockIdx.x, u = threadIdx.x;
    const float* g = gbuf + (size_t)sb*1024;
    float gi = g[u], gf = g[256+u], gg = g[512+u], go = g[768+u];
    float cv = c[(size_t)sb*256+u];
    cv = sigmf_(gf)*cv + sigmf_(gi)*tanhf(gg);
    float hv = sigmf_(go)*tanhf(cv);
    c[(size_t)sb*256+u] = cv;
    h[(size_t)sb*256+u] = hv;
    dec_out_j[(size_t)sb*256+u] = hv;
}

// ---------------- logits + fused online logsumexp + tgt/EOS extraction ----------------
// grid (315, 2): 64 rows/block, v-half (2048 v's in 16 tiles of 128). 256 threads, micro 4x8, BK=32.
__global__ __launch_bounds__(256) void k_logits(
    const float* __restrict__ Arows, const float* __restrict__ emb,
    const float* __restrict__ e2v_b, const int* __restrict__ x,
    float* __restrict__ pm, float* __restrict__ ps,
    float* __restrict__ pzt, float* __restrict__ pze)
{
    const int NROW = 20160;
    __shared__ float As[32][68];
    __shared__ float Bs[32][132];
    __shared__ int   tgt_s[64];
    __shared__ float eb_s[128];
    int tid = threadIdx.x;
    int rb = blockIdx.x, hf = blockIdx.y;
    int r0 = rb * 64;
    if (tid < 64){
        int r = r0 + tid;
        int t = r / 4032, sb = r % 4032;
        int s = sb >> 5, b = sb & 31;
        int m = s + 1 + t;
        tgt_s[tid] = (m < 128) ? x[b*128 + m] : 0;
    }
    int tx = tid & 15, ty = tid >> 4;
    float rm[4], rs[4], rzt[4], rze[4];
    #pragma unroll
    for (int i = 0; i < 4; i++){ rm[i] = -1e30f; rs[i] = 0.f; rzt[i] = -1e30f; rze[i] = -1e30f; }
    int lrA = tid >> 2, lkA = (tid & 3) * 8;
    int lrB = tid >> 1, lkB = (tid & 1) * 16;
    const float* Abase = Arows + (size_t)(r0 + lrA)*256 + lkA;
    for (int vt = 0; vt < 16; vt++){
        __syncthreads();   // protect eb_s / LDS from previous tile's readers
        int v0 = hf*2048 + vt*128;
        if (tid < 128){
            int v = v0 + tid;
            eb_s[tid] = (v < 4000) ? e2v_b[v] : 0.0f;
        }
        int vb = v0 + lrB;
        const float* Bbase = emb + (size_t)((vb < 4000) ? vb : 0)*256 + lkB;
        float acc[4][8] = {};
        for (int kc = 0; kc < 256; kc += 32){
            float4 a0 = *(const float4*)(Abase + kc);
            float4 a1 = *(const float4*)(Abase + kc + 4);
            As[lkA+0][lrA]=a0.x; As[lkA+1][lrA]=a0.y; As[lkA+2][lrA]=a0.z; As[lkA+3][lrA]=a0.w;
            As[lkA+4][lrA]=a1.x; As[lkA+5][lrA]=a1.y; As[lkA+6][lrA]=a1.z; As[lkA+7][lrA]=a1.w;
            const float* Bp = Bbase + kc;
            float4 b0v = *(const float4*)(Bp);
            float4 b1v = *(const float4*)(Bp+4);
            float4 b2v = *(const float4*)(Bp+8);
            float4 b3v = *(const float4*)(Bp+12);
            Bs[lkB+ 0][lrB]=b0v.x; Bs[lkB+ 1][lrB]=b0v.y; Bs[lkB+ 2][lrB]=b0v.z; Bs[lkB+ 3][lrB]=b0v.w;
            Bs[lkB+ 4][lrB]=b1v.x; Bs[lkB+ 5][lrB]=b1v.y; Bs[lkB+ 6][lrB]=b1v.z; Bs[lkB+ 7][lrB]=b1v.w;
            Bs[lkB+ 8][lrB]=b2v.x; Bs[lkB+ 9][lrB]=b2v.y; Bs[lkB+10][lrB]=b2v.z; Bs[lkB+11][lrB]=b2v.w;
            Bs[lkB+12][lrB]=b3v.x; Bs[lkB+13][lrB]=b3v.y; Bs[lkB+14][lrB]=b3v.z; Bs[lkB+15][lrB]=b3v.w;
            __syncthreads();
            #pragma unroll
            for (int k = 0; k < 32; k++){
                float4 a4 = *(const float4*)&As[k][ty*4];
                float4 p0 = *(const float4*)&Bs[k][tx*8];
                float4 p1 = *(const float4*)&Bs[k][tx*8+4];
                float av[4] = {a4.x,a4.y,a4.z,a4.w};
                float bv[8] = {p0.x,p0.y,p0.z,p0.w,p1.x,p1.y,p1.z,p1.w};
                #pragma unroll
                for (int i = 0; i < 4; i++){
                    #pragma unroll
                    for (int j = 0; j < 8; j++) acc[i][j] += av[i]*bv[j];
                }
            }
            __syncthreads();
        }
        #pragma unroll
        for (int i = 0; i < 4; i++){
            float z[8];
            float tm = -1e30f;
            #pragma unroll
            for (int j = 0; j < 8; j++){
                int v = v0 + tx*8 + j;
                z[j] = acc[i][j] + eb_s[tx*8+j];
                if (v < 4000) tm = fmaxf(tm, z[j]);
            }
            if (tm > -1e29f){
                float mn = fmaxf(rm[i], tm);
                float ssum = rs[i]*expf(rm[i]-mn);
                #pragma unroll
                for (int j = 0; j < 8; j++){
                    int v = v0 + tx*8 + j;
                    if (v < 4000) ssum += expf(z[j]-mn);
                }
                rm[i] = mn; rs[i] = ssum;
            }
            int tg = tgt_s[ty*4+i];
            #pragma unroll
            for (int j = 0; j < 8; j++){
                int v = v0 + tx*8 + j;
                if (v == tg) rzt[i] = z[j];
                if (v == 3)  rze[i] = z[j];
            }
        }
    }
    // reduce across the 16 lanes (tx) sharing each row group
    #pragma unroll
    for (int i = 0; i < 4; i++){
        for (int off = 1; off < 16; off <<= 1){
            float om = __shfl_xor(rm[i], off, 64);
            float os = __shfl_xor(rs[i], off, 64);
            float mn = fmaxf(rm[i], om);
            rs[i] = rs[i]*expf(rm[i]-mn) + os*expf(om-mn);
            rm[i] = mn;
            rzt[i] = fmaxf(rzt[i], __shfl_xor(rzt[i], off, 64));
            rze[i] = fmaxf(rze[i], __shfl_xor(rze[i], off, 64));
        }
    }
    if (tx == 0){
        #pragma unroll
        for (int i = 0; i < 4; i++){
            int r = r0 + ty*4 + i;
            pm [hf*NROW + r] = rm[i];
            ps [hf*NROW + r] = rs[i];
            pzt[hf*NROW + r] = rzt[i];
            pze[hf*NROW + r] = rze[i];
        }
    }
}

// ---------------- combine v-halves -> tlp / eos ----------------
__global__ __launch_bounds__(256) void k_combine(
    const float* __restrict__ pm, const float* __restrict__ ps,
    const float* __restrict__ pzt, const float* __restrict__ pze,
    float* __restrict__ tlp, float* __restrict__ eosb)
{
    int r = blockIdx.x*256 + threadIdx.x;
    if (r >= 20160) return;
    float m0 = pm[r], m1 = pm[20160+r];
    float s0 = ps[r], s1 = ps[20160+r];
    float M = fmaxf(m0, m1);
    float lse = M + logf(s0*expf(m0-M) + s1*expf(m1-M));
    float zt = fmaxf(pzt[r], pzt[20160+r]);
    float ze = fmaxf(pze[r], pze[20160+r]);
    int t = r / 4032, sb = r % 4032;
    int s = sb >> 5, b = sb & 31;
    if (t < 4)  tlp[(t*126+s)*32 + b]      = zt - lse;
    if (t >= 1) eosb[((t-1)*126+s)*32 + b] = ze - lse;
}

// ---------------- segmental DP + final reduction ----------------
// 1 block, 128 threads (k = tid/32, b = tid&31)
__global__ __launch_bounds__(128) void k_finalize(
    const float* __restrict__ tlp, const float* __restrict__ eosb,
    const float* __restrict__ is_s, const int* __restrict__ lengths,
    float* __restrict__ seg_g, float* __restrict__ out)
{
    int tid = threadIdx.x;
    int k = tid >> 5, b = tid & 31;
    for (int s = 0; s < 126; s++){
        float cum = 0.f;
        for (int kk = 0; kk <= k; kk++) cum += tlp[(kk*126+s)*32 + b];
        if (k >= 1){
            for (int kk = 1; kk <= k; kk++){
                int m = s+1+kk;
                if (m < 128) cum += is_s[m*32+b];
            }
            cum += is_s[(s+1)*32 + b];
        }
        float lp = cum + eosb[(k*126+s)*32 + b];
        int jl = min(4, 126 - s);
        if (k >= jl) lp = LOGNEG;
        seg_g[(s*4+k)*32 + b] = lp;
    }
    __threadfence_block();
    __syncthreads();
    __shared__ float nll_s[32];
    if (tid < 32){
        int target = lengths[tid] - 2;
        float b0 = 0.f, b1 = LOGNEG, b2 = LOGNEG, b3 = LOGNEG;
        float nllb = 0.f;   // covers target==0 (alpha[0]=0)
        for (int e = 1; e <= 126; e++){
            float v0 = b0 + seg_g[((e-1)*4+0)*32 + tid];
            float v1 = b1 + ((e >= 2) ? seg_g[((e-2)*4+1)*32 + tid] : LOGNEG);
            float v2 = b2 + ((e >= 3) ? seg_g[((e-3)*4+2)*32 + tid] : LOGNEG);
            float v3 = b3 + ((e >= 4) ? seg_g[((e-4)*4+3)*32 + tid] : LOGNEG);
            float mx = fmaxf(fmaxf(v0,v1), fmaxf(v2,v3));
            float a = mx + logf(expf(v0-mx)+expf(v1-mx)+expf(v2-mx)+expf(v3-mx));
            if (e == target) nllb = -a;
            b3 = b2; b2 = b1; b1 = b0; b0 = a;
        }
        nll_s[tid] = nllb;
    }
    __syncthreads();
    if (tid == 0){
        float tot = 0.f; int lsum = 0;
        for (int i = 0; i < 32; i++){ tot += nll_s[i]; lsum += lengths[i]; }
        out[0] = tot / (float)(lsum - 64);
    }
}

extern "C" void kernel_launch(void* const* d_in, const int* in_sizes, int n_in,
                              void* d_out, int out_size, void* d_ws, size_t ws_size,
                              hipStream_t stream)
{
    const int*   x        = (const int*)  d_in[0];
    const int*   lengths  = (const int*)  d_in[1];
    const float* emb      = (const float*)d_in[2];
    const float* e2v_b    = (const float*)d_in[3];
    const float* enc_Wih  = (const float*)d_in[4];
    const float* enc_Whh  = (const float*)d_in[5];
    const float* enc_bih  = (const float*)d_in[6];
    const float* enc_bhh  = (const float*)d_in[7];
    const float* enc_h0   = (const float*)d_in[8];
    const float* enc_c0   = (const float*)d_in[9];
    const float* dec_Wih  = (const float*)d_in[10];
    const float* dec_Whh  = (const float*)d_in[11];
    const float* dec_bih  = (const float*)d_in[12];
    const float* dec_bhh  = (const float*)d_in[13];
    const float* dht_W    = (const float*)d_in[14];
    const float* dht_b    = (const float*)d_in[15];
    const float* sos_W    = (const float*)d_in[16];
    const float* sos_b    = (const float*)d_in[17];
    float* out = (float*)d_out;

    char* wsb = (char*)d_ws;
    size_t off = 0;
    auto alloc = [&](size_t elems)->float*{
        float* p = (float*)(wsb + off);
        off += ((elems*sizeof(float) + 255)/256)*256;
        return p;
    };
    float* emb_in  = alloc((size_t)4096*256);
    float* is_s    = alloc(4096);
    float* Xg_enc  = alloc((size_t)4096*1024);   // reused as XgI after encoder
    float* WhhT    = alloc((size_t)256*1024);
    float* enc_out = alloc((size_t)4096*256);
    float* sos     = alloc((size_t)4032*256);
    float* dec_h   = alloc((size_t)4032*256);
    float* dec_c   = alloc((size_t)4032*256);
    float* gbuf    = alloc((size_t)4032*1024);
    float* dec_out = alloc((size_t)5*4032*256);
    float* bias_e  = alloc(1024);
    float* bias_d  = alloc(1024);
    float* pm      = alloc((size_t)2*20160);
    float* ps      = alloc((size_t)2*20160);
    float* pzt     = alloc((size_t)2*20160);
    float* pze     = alloc((size_t)2*20160);
    float* tlp     = alloc((size_t)4*126*32);
    float* eosb    = alloc((size_t)4*126*32);
    float* seg_g   = alloc((size_t)126*4*32);
    (void)ws_size; (void)in_sizes; (void)n_in; (void)out_size;

    // 1. prep (transpose enc_Whh, bias sums)
    k_prep<<<1024, 256, 0, stream>>>(enc_Whh, WhhT, enc_bih, enc_bhh, bias_e, dec_bih, dec_bhh, bias_d);
    // 2. embeddings + is_single
    k_embed<<<4096, 256, 0, stream>>>(x, emb, emb_in, is_s);
    // 3. encoder input-side gates: Xg_enc = emb_in @ enc_Wih^T + (bih+bhh)
    k_gemm<<<dim3(16,64), 256, 0, stream>>>(emb_in, enc_Wih, bias_e, Xg_enc, 256, 1024, GF_BIAS, nullptr, nullptr, 0);
    // 4. encoder recurrence (batch-row-parallel, no grid sync)
    k_enc_rnn<<<32, 1024, 0, stream>>>(Xg_enc, WhhT, enc_h0, enc_c0, enc_out);
    // 5. sos = enc_prev @ sos_W^T + sos_b   (enc_prev = enc_out rows 0..4031)
    k_gemm<<<dim3(4,63), 256, 0, stream>>>(enc_out, sos_W, sos_b, sos, 256, 256, GF_BIAS, nullptr, nullptr, 0);
    // 6. dec_h0 = tanh(enc_prev @ dht_W^T + dht_b)
    k_gemm<<<dim3(4,63), 256, 0, stream>>>(enc_out, dht_W, dht_b, dec_h, 256, 256, GF_BIAS|GF_TANH, nullptr, nullptr, 0);
    // 7. dec_c = 0
    hipMemsetAsync(dec_c, 0, (size_t)4032*256*sizeof(float), stream);
    // 8. input gates for decoder step 0: gbuf = sos @ dec_Wih^T + (bih+bhh)
    k_gemm<<<dim3(16,63), 256, 0, stream>>>(sos, dec_Wih, bias_d, gbuf, 256, 1024, GF_BIAS, nullptr, nullptr, 0);
    // 9. input gates for steps >=1 (all token embeddings): XgI = emb_in @ dec_Wih^T + bias   (reuses Xg_enc)
    k_gemm<<<dim3(16,64), 256, 0, stream>>>(emb_in, dec_Wih, bias_d, Xg_enc, 256, 1024, GF_BIAS, nullptr, nullptr, 0);
    // 10. decoder recurrence (5 steps)
    for (int j = 0; j < 5; j++){
        if (j == 0){
            k_gemm<<<dim3(16,63), 256, 0, stream>>>(dec_h, dec_Whh, nullptr, gbuf, 256, 1024, GF_ACC, nullptr, nullptr, 0);
        } else {
            k_gemm<<<dim3(16,63), 256, 0, stream>>>(dec_h, dec_Whh, nullptr, gbuf, 256, 1024, GF_DECSTEP, Xg_enc, bias_d, j);
        }
        k_pointwise<<<4032, 256, 0, stream>>>(gbuf, dec_h, dec_c, dec_out + (size_t)j*4032*256);
    }
    // 11. fused logits + logsumexp + tgt/EOS extraction
    k_logits<<<dim3(315,2), 256, 0, stream>>>(dec_out, emb, e2v_b, x, pm, ps, pzt, pze);
    // 12. combine halves
    k_combine<<<79, 256, 0, stream>>>(pm, ps, pzt, pze, tlp, eosb);
    // 13. segmental DP + reduction
    k_finalize<<<1, 128, 0, stream>>>(tlp, eosb, is_s, lengths, seg_g, out);
}